// Round 2
// baseline (500.926 us; speedup 1.0000x reference)
//
#include <hip/hip_runtime.h>
#include <hip/hip_bf16.h>

// Problem: B=2,S=8192 -> TOK=16384 tokens; H=1024; DFF=4096.
// out[t] = mask[t] ? relu((h[t]*w[t]) @ W1 + b1) @ W2 + b2 : 0
// w = sigmoid(h@Wg+bg); mask = (logit>=0) | (label==-100)
// R2: gemm2 retiled 128x128 -> 64x128 (2x blocks; was grid-starved at 568
// blocks / 2.2 per CU, Occ 21.6%, MfmaUtil 22%).

#define TOK 16384
#define HID 1024
#define FF  4096

typedef __attribute__((ext_vector_type(8))) __bf16 bf16x8;
typedef __attribute__((ext_vector_type(4))) float f32x4;

__device__ __forceinline__ void gload_lds16(const void* g, void* l) {
  // async global->LDS, 16B per lane; LDS dest = wave-uniform base + lane*16
  __builtin_amdgcn_global_load_lds((const __attribute__((address_space(1))) void*)g,
                                   (__attribute__((address_space(3))) void*)l, 16, 0, 0);
}

// ---------------- weight transpose + fp32->bf16 cast ----------------
// src fp32 [R][C] -> dst bf16 [C][R]; R,C multiples of 32. block (32,8)
__global__ __launch_bounds__(256) void k_transpose(const float* __restrict__ src,
                                                   __hip_bfloat16* __restrict__ dst,
                                                   int R, int C) {
  __shared__ float tile[32][33];
  const int c0 = blockIdx.x * 32, r0 = blockIdx.y * 32;
  const int tx = threadIdx.x, ty = threadIdx.y;
#pragma unroll
  for (int i = 0; i < 32; i += 8)
    tile[ty + i][tx] = src[(size_t)(r0 + ty + i) * C + (c0 + tx)];
  __syncthreads();
#pragma unroll
  for (int i = 0; i < 32; i += 8)
    dst[(size_t)(c0 + ty + i) * R + (r0 + tx)] = __float2bfloat16(tile[tx][ty + i]);
}

// ---------------- gate + compact + zero dropped rows ----------------
__global__ __launch_bounds__(256) void k_gate(const float* __restrict__ h,
                                              const float* __restrict__ wg,
                                              const float* __restrict__ bgp,
                                              const int* __restrict__ labels,
                                              float* __restrict__ out,
                                              __hip_bfloat16* __restrict__ A,
                                              int* __restrict__ idx,
                                              int* __restrict__ cnt) {
  const int t = blockIdx.x;
  const int tid = threadIdx.x;
  const float4 hv = ((const float4*)(h + (size_t)t * HID))[tid];
  const float4 gv = ((const float4*)wg)[tid];
  float d = hv.x * gv.x + hv.y * gv.y + hv.z * gv.z + hv.w * gv.w;
#pragma unroll
  for (int o = 32; o > 0; o >>= 1) d += __shfl_down(d, o, 64);
  __shared__ float ps[4];
  __shared__ int mrow;
  if ((tid & 63) == 0) ps[tid >> 6] = d;
  __syncthreads();
  const float logit = ps[0] + ps[1] + ps[2] + ps[3] + bgp[0];
  const bool keep = (logit >= 0.0f) || (labels[t] == -100);
  if (keep) {
    if (tid == 0) { int m = atomicAdd(cnt, 1); idx[m] = t; mrow = m; }
    __syncthreads();
    const int m = mrow;
    const float w = 1.0f / (1.0f + __expf(-logit));
    union { ushort4 u; __hip_bfloat16 b[4]; } pk;
    pk.b[0] = __float2bfloat16(hv.x * w);
    pk.b[1] = __float2bfloat16(hv.y * w);
    pk.b[2] = __float2bfloat16(hv.z * w);
    pk.b[3] = __float2bfloat16(hv.w * w);
    ((ushort4*)(A + (size_t)m * HID))[tid] = pk.u;
  } else {
    ((float4*)(out + (size_t)t * HID))[tid] = make_float4(0.f, 0.f, 0.f, 0.f);
  }
}

// ---------------- GEMM1: Act = relu(A @ W1 + b1), bf16 out ----------------
// 128x128 tile, BK=32, 4 waves each 64x64 via 4x4 of 16x16x32 MFMA
__global__ __launch_bounds__(256, 2) void k_gemm1(const __hip_bfloat16* __restrict__ A,
                                                  const __hip_bfloat16* __restrict__ Bt,
                                                  const float* __restrict__ bias,
                                                  __hip_bfloat16* __restrict__ Act,
                                                  const int* __restrict__ cnt) {
  const int Mc = *cnt;
  const int m0 = blockIdx.x * 128;
  if (m0 >= Mc) return;
  const int n0 = blockIdx.y * 128;

  __shared__ __hip_bfloat16 lA[128 * 32];
  __shared__ __hip_bfloat16 lB[128 * 32];

  const int tid = threadIdx.x;
  const int wave = tid >> 6, lane = tid & 63;
  const int wr = (wave >> 1) * 64, wc = (wave & 1) * 64;
  const int srow = wave * 16 + (lane >> 2);
  const int sch  = (lane & 3) * 8;
  const int fm = lane & 15, fk = (lane >> 4) * 8, quad = lane >> 4;

  f32x4 acc[4][4] = {};

  const __hip_bfloat16* gA = A  + (size_t)(m0 + srow) * HID + sch;
  const __hip_bfloat16* gB = Bt + (size_t)(n0 + srow) * HID + sch;
  char* dA = (char*)lA + wave * 1024;
  char* dB = (char*)lB + wave * 1024;

  for (int kt = 0; kt < HID; kt += 32) {
    __syncthreads();
    gload_lds16(gA + kt, dA);
    gload_lds16(gA + (size_t)64 * HID + kt, dA + 4096);
    gload_lds16(gB + kt, dB);
    gload_lds16(gB + (size_t)64 * HID + kt, dB + 4096);
    __syncthreads();
    bf16x8 af[4], bb[4];
#pragma unroll
    for (int i = 0; i < 4; ++i) af[i] = *(const bf16x8*)&lA[(wr + i * 16 + fm) * 32 + fk];
#pragma unroll
    for (int j = 0; j < 4; ++j) bb[j] = *(const bf16x8*)&lB[(wc + j * 16 + fm) * 32 + fk];
#pragma unroll
    for (int i = 0; i < 4; ++i)
#pragma unroll
      for (int j = 0; j < 4; ++j)
        acc[i][j] = __builtin_amdgcn_mfma_f32_16x16x32_bf16(af[i], bb[j], acc[i][j], 0, 0, 0);
  }

#pragma unroll
  for (int j = 0; j < 4; ++j) {
    const int col = n0 + wc + j * 16 + fm;
    const float bv = bias[col];
#pragma unroll
    for (int i = 0; i < 4; ++i) {
      const int rbase = m0 + wr + i * 16 + quad * 4;
#pragma unroll
      for (int r = 0; r < 4; ++r) {
        float v = acc[i][j][r] + bv;
        v = v > 0.f ? v : 0.f;
        Act[(size_t)(rbase + r) * FF + col] = __float2bfloat16(v);
      }
    }
  }
}

// ---------------- GEMM2: out[idx[m]] = Act @ W2 + b2, fp32 scatter ----------------
// R2: 64x128 tile, BK=32, 4 waves each 32x64 via 2x4 of 16x16x32 MFMA.
// 2x more blocks than 128x128 (grid was 568 blocks -> latency-bound).
__global__ __launch_bounds__(256, 4) void k_gemm2(const __hip_bfloat16* __restrict__ Act,
                                                  const __hip_bfloat16* __restrict__ Bt,
                                                  const float* __restrict__ bias,
                                                  const int* __restrict__ idx,
                                                  float* __restrict__ out,
                                                  const int* __restrict__ cnt) {
  const int Mc = *cnt;
  const int m0 = blockIdx.x * 64;
  if (m0 >= Mc) return;
  const int n0 = blockIdx.y * 128;

  __shared__ __hip_bfloat16 lA[64 * 32];    // 4 KiB
  __shared__ __hip_bfloat16 lB[128 * 32];   // 8 KiB

  const int tid = threadIdx.x;
  const int wave = tid >> 6, lane = tid & 63;
  const int wr = (wave >> 1) * 32, wc = (wave & 1) * 64;
  const int srow = wave * 16 + (lane >> 2);   // [0,64)
  const int sch  = (lane & 3) * 8;
  const int fm = lane & 15, fk = (lane >> 4) * 8, quad = lane >> 4;

  f32x4 acc[2][4] = {};

  const __hip_bfloat16* gA = Act + (size_t)(m0 + srow) * FF + sch;
  const __hip_bfloat16* gB = Bt  + (size_t)(n0 + srow) * FF + sch;
  char* dA = (char*)lA + wave * 1024;
  char* dB = (char*)lB + wave * 1024;

  for (int kt = 0; kt < FF; kt += 32) {
    __syncthreads();
    gload_lds16(gA + kt, dA);                               // A: 64 rows, 1 call
    gload_lds16(gB + kt, dB);                               // B rows [0,64)
    gload_lds16(gB + (size_t)64 * FF + kt, dB + 4096);      // B rows [64,128)
    __syncthreads();
    bf16x8 af[2], bb[4];
#pragma unroll
    for (int i = 0; i < 2; ++i) af[i] = *(const bf16x8*)&lA[(wr + i * 16 + fm) * 32 + fk];
#pragma unroll
    for (int j = 0; j < 4; ++j) bb[j] = *(const bf16x8*)&lB[(wc + j * 16 + fm) * 32 + fk];
#pragma unroll
    for (int i = 0; i < 2; ++i)
#pragma unroll
      for (int j = 0; j < 4; ++j)
        acc[i][j] = __builtin_amdgcn_mfma_f32_16x16x32_bf16(af[i], bb[j], acc[i][j], 0, 0, 0);
  }

#pragma unroll
  for (int i = 0; i < 2; ++i) {
#pragma unroll
    for (int r = 0; r < 4; ++r) {
      const int m = m0 + wr + i * 16 + quad * 4 + r;
      if (m < Mc) {
        const int t = idx[m];
        float* orow = out + (size_t)t * HID + n0 + wc + fm;
#pragma unroll
        for (int j = 0; j < 4; ++j)
          orow[j * 16] = acc[i][j][r] + bias[n0 + wc + j * 16 + fm];
      }
    }
  }
}

// ---------------- launch ----------------
extern "C" void kernel_launch(void* const* d_in, const int* in_sizes, int n_in,
                              void* d_out, int out_size, void* d_ws, size_t ws_size,
                              hipStream_t stream) {
  const float* h   = (const float*)d_in[0];
  const float* Wg  = (const float*)d_in[3];
  const float* bg  = (const float*)d_in[4];
  const float* W1  = (const float*)d_in[5];
  const float* b1  = (const float*)d_in[6];
  const float* W2  = (const float*)d_in[7];
  const float* b2  = (const float*)d_in[8];
  const int*  labels = (const int*)d_in[9];
  float* out = (float*)d_out;

  char* ws = (char*)d_ws;
  int* cnt            = (int*)(ws + 0);
  int* idx            = (int*)(ws + 1024);
  __hip_bfloat16* W1t = (__hip_bfloat16*)(ws + (1u  << 17));   // [FF][HID]
  __hip_bfloat16* W2t = (__hip_bfloat16*)(ws + (16u << 20));   // [HID][FF]
  __hip_bfloat16* A   = (__hip_bfloat16*)(ws + (32u << 20));   // [TOK][HID]
  __hip_bfloat16* Act = (__hip_bfloat16*)(ws + (64ull << 20)); // [TOK][FF]

  hipMemsetAsync(cnt, 0, 4, stream);
  k_transpose<<<dim3(FF / 32, HID / 32), dim3(32, 8), 0, stream>>>(W1, W1t, HID, FF);
  k_transpose<<<dim3(HID / 32, FF / 32), dim3(32, 8), 0, stream>>>(W2, W2t, FF, HID);
  k_gate<<<TOK, 256, 0, stream>>>(h, Wg, bg, labels, out, A, idx, cnt);
  k_gemm1<<<dim3(TOK / 128, FF / 128), 256, 0, stream>>>(A, W1t, b1, Act, cnt);
  k_gemm2<<<dim3(TOK / 64, HID / 128), 256, 0, stream>>>(Act, W2t, b2, idx, out, cnt);
}

// Round 4
// 436.675 us; speedup vs baseline: 1.1471x; 1.1471x over previous
//
#include <hip/hip_runtime.h>
#include <hip/hip_bf16.h>

// Problem: B=2,S=8192 -> TOK=16384 tokens; H=1024; DFF=4096.
// out[t] = mask[t] ? relu((h[t]*w[t]) @ W1 + b1) @ W2 + b2 : 0
// w = sigmoid(h@Wg+bg); mask = (logit>=0) | (label==-100)
// R4: R3 with the staging-stride bug fixed: BK=64 LDS row = 128 B, so a
// wave's 32-row region = 4096 B and each gload call covers 1024 B (R3 used
// 8192/2048 -> OOB LDS writes -> NaN). XOR swizzle + BK=64 otherwise as R3.

#define TOK 16384
#define HID 1024
#define FF  4096

typedef __attribute__((ext_vector_type(8))) __bf16 bf16x8;
typedef __attribute__((ext_vector_type(4))) float f32x4;

__device__ __forceinline__ void gload_lds16(const void* g, void* l) {
  // async global->LDS, 16B per lane; LDS dest = wave-uniform base + lane*16
  __builtin_amdgcn_global_load_lds((const __attribute__((address_space(1))) void*)g,
                                   (__attribute__((address_space(3))) void*)l, 16, 0, 0);
}

// ---------------- weight transpose + fp32->bf16 cast ----------------
__global__ __launch_bounds__(256) void k_transpose(const float* __restrict__ src,
                                                   __hip_bfloat16* __restrict__ dst,
                                                   int R, int C) {
  __shared__ float tile[32][33];
  const int c0 = blockIdx.x * 32, r0 = blockIdx.y * 32;
  const int tx = threadIdx.x, ty = threadIdx.y;
#pragma unroll
  for (int i = 0; i < 32; i += 8)
    tile[ty + i][tx] = src[(size_t)(r0 + ty + i) * C + (c0 + tx)];
  __syncthreads();
#pragma unroll
  for (int i = 0; i < 32; i += 8)
    dst[(size_t)(c0 + ty + i) * R + (r0 + tx)] = __float2bfloat16(tile[tx][ty + i]);
}

// ---------------- gate + compact + zero dropped rows ----------------
__global__ __launch_bounds__(256) void k_gate(const float* __restrict__ h,
                                              const float* __restrict__ wg,
                                              const float* __restrict__ bgp,
                                              const int* __restrict__ labels,
                                              float* __restrict__ out,
                                              __hip_bfloat16* __restrict__ A,
                                              int* __restrict__ idx,
                                              int* __restrict__ cnt) {
  const int t = blockIdx.x;
  const int tid = threadIdx.x;
  const float4 hv = ((const float4*)(h + (size_t)t * HID))[tid];
  const float4 gv = ((const float4*)wg)[tid];
  float d = hv.x * gv.x + hv.y * gv.y + hv.z * gv.z + hv.w * gv.w;
#pragma unroll
  for (int o = 32; o > 0; o >>= 1) d += __shfl_down(d, o, 64);
  __shared__ float ps[4];
  __shared__ int mrow;
  if ((tid & 63) == 0) ps[tid >> 6] = d;
  __syncthreads();
  const float logit = ps[0] + ps[1] + ps[2] + ps[3] + bgp[0];
  const bool keep = (logit >= 0.0f) || (labels[t] == -100);
  if (keep) {
    if (tid == 0) { int m = atomicAdd(cnt, 1); idx[m] = t; mrow = m; }
    __syncthreads();
    const int m = mrow;
    const float w = 1.0f / (1.0f + __expf(-logit));
    union { ushort4 u; __hip_bfloat16 b[4]; } pk;
    pk.b[0] = __float2bfloat16(hv.x * w);
    pk.b[1] = __float2bfloat16(hv.y * w);
    pk.b[2] = __float2bfloat16(hv.z * w);
    pk.b[3] = __float2bfloat16(hv.w * w);
    ((ushort4*)(A + (size_t)m * HID))[tid] = pk.u;
  } else {
    ((float4*)(out + (size_t)t * HID))[tid] = make_float4(0.f, 0.f, 0.f, 0.f);
  }
}

// ---------------- GEMM core layout ----------------
// LDS tile: 128 rows x 64 k (bf16), row stride 64 elems = 128 B.
// Staging: lane l, call c -> row = wave*32 + c*8 + (l>>3) = r,
//   global chunk g = (l&7) ^ (r&7); stored position p = g ^ (r&7) = l&7,
//   LDS dest = base + wave*4096 + c*1024 + l*16.   (srow == r&7)
// Fragment read of global chunk g of row r at position g ^ (r&7); for
// fragment rows r&7 == fm&7, so position = (ks*4+quad) ^ (fm&7) -> per-quad
// lanes cover all 8 bank-quads (2-way aliasing = free).

// GEMM1: Act = relu(A @ W1t^T + b1), bf16 out. K=HID=1024.
__global__ __launch_bounds__(256, 2) void k_gemm1(const __hip_bfloat16* __restrict__ A,
                                                  const __hip_bfloat16* __restrict__ Bt,
                                                  const float* __restrict__ bias,
                                                  __hip_bfloat16* __restrict__ Act,
                                                  const int* __restrict__ cnt) {
  const int Mc = *cnt;
  const int m0 = blockIdx.x * 128;
  if (m0 >= Mc) return;
  const int n0 = blockIdx.y * 128;

  __shared__ __hip_bfloat16 lA[128 * 64];  // 16 KiB
  __shared__ __hip_bfloat16 lB[128 * 64];  // 16 KiB

  const int tid = threadIdx.x;
  const int wave = tid >> 6, lane = tid & 63;
  const int wr = (wave >> 1) * 64, wc = (wave & 1) * 64;
  const int fm = lane & 15, quad = lane >> 4;

  const int srow = (lane >> 3);                       // 0..7
  const int sg   = ((lane & 7) ^ srow) * 8;           // global elem offset

  f32x4 acc[4][4] = {};

  const __hip_bfloat16* gA = A  + (size_t)(m0 + wave * 32 + srow) * HID + sg;
  const __hip_bfloat16* gB = Bt + (size_t)(n0 + wave * 32 + srow) * HID + sg;
  char* dA = (char*)lA + wave * 4096;
  char* dB = (char*)lB + wave * 4096;

  for (int kt = 0; kt < HID; kt += 64) {
    __syncthreads();
#pragma unroll
    for (int c = 0; c < 4; ++c) {
      gload_lds16(gA + (size_t)(c * 8) * HID + kt, dA + c * 1024);
      gload_lds16(gB + (size_t)(c * 8) * HID + kt, dB + c * 1024);
    }
    __syncthreads();
#pragma unroll
    for (int ks = 0; ks < 2; ++ks) {
      bf16x8 af[4], bb[4];
#pragma unroll
      for (int i = 0; i < 4; ++i)
        af[i] = *(const bf16x8*)&lA[(wr + i * 16 + fm) * 64 + (((ks * 4 + quad) ^ (fm & 7)) * 8)];
#pragma unroll
      for (int j = 0; j < 4; ++j)
        bb[j] = *(const bf16x8*)&lB[(wc + j * 16 + fm) * 64 + (((ks * 4 + quad) ^ (fm & 7)) * 8)];
#pragma unroll
      for (int i = 0; i < 4; ++i)
#pragma unroll
        for (int j = 0; j < 4; ++j)
          acc[i][j] = __builtin_amdgcn_mfma_f32_16x16x32_bf16(af[i], bb[j], acc[i][j], 0, 0, 0);
    }
  }

#pragma unroll
  for (int j = 0; j < 4; ++j) {
    const int col = n0 + wc + j * 16 + fm;
    const float bv = bias[col];
#pragma unroll
    for (int i = 0; i < 4; ++i) {
      const int rbase = m0 + wr + i * 16 + quad * 4;
#pragma unroll
      for (int r = 0; r < 4; ++r) {
        float v = acc[i][j][r] + bv;
        v = v > 0.f ? v : 0.f;
        Act[(size_t)(rbase + r) * FF + col] = __float2bfloat16(v);
      }
    }
  }
}

// GEMM2: out[idx[m]] = Act @ W2t^T + b2, fp32 scatter. K=FF=4096.
__global__ __launch_bounds__(256, 2) void k_gemm2(const __hip_bfloat16* __restrict__ Act,
                                                  const __hip_bfloat16* __restrict__ Bt,
                                                  const float* __restrict__ bias,
                                                  const int* __restrict__ idx,
                                                  float* __restrict__ out,
                                                  const int* __restrict__ cnt) {
  const int Mc = *cnt;
  const int m0 = blockIdx.x * 128;
  if (m0 >= Mc) return;
  const int n0 = blockIdx.y * 128;

  __shared__ __hip_bfloat16 lA[128 * 64];
  __shared__ __hip_bfloat16 lB[128 * 64];

  const int tid = threadIdx.x;
  const int wave = tid >> 6, lane = tid & 63;
  const int wr = (wave >> 1) * 64, wc = (wave & 1) * 64;
  const int fm = lane & 15, quad = lane >> 4;
  const int srow = (lane >> 3);
  const int sg   = ((lane & 7) ^ srow) * 8;

  f32x4 acc[4][4] = {};

  const __hip_bfloat16* gA = Act + (size_t)(m0 + wave * 32 + srow) * FF + sg;
  const __hip_bfloat16* gB = Bt  + (size_t)(n0 + wave * 32 + srow) * FF + sg;
  char* dA = (char*)lA + wave * 4096;
  char* dB = (char*)lB + wave * 4096;

  for (int kt = 0; kt < FF; kt += 64) {
    __syncthreads();
#pragma unroll
    for (int c = 0; c < 4; ++c) {
      gload_lds16(gA + (size_t)(c * 8) * FF + kt, dA + c * 1024);
      gload_lds16(gB + (size_t)(c * 8) * FF + kt, dB + c * 1024);
    }
    __syncthreads();
#pragma unroll
    for (int ks = 0; ks < 2; ++ks) {
      bf16x8 af[4], bb[4];
#pragma unroll
      for (int i = 0; i < 4; ++i)
        af[i] = *(const bf16x8*)&lA[(wr + i * 16 + fm) * 64 + (((ks * 4 + quad) ^ (fm & 7)) * 8)];
#pragma unroll
      for (int j = 0; j < 4; ++j)
        bb[j] = *(const bf16x8*)&lB[(wc + j * 16 + fm) * 64 + (((ks * 4 + quad) ^ (fm & 7)) * 8)];
#pragma unroll
      for (int i = 0; i < 4; ++i)
#pragma unroll
        for (int j = 0; j < 4; ++j)
          acc[i][j] = __builtin_amdgcn_mfma_f32_16x16x32_bf16(af[i], bb[j], acc[i][j], 0, 0, 0);
    }
  }

#pragma unroll
  for (int i = 0; i < 4; ++i) {
#pragma unroll
    for (int r = 0; r < 4; ++r) {
      const int m = m0 + wr + i * 16 + quad * 4 + r;
      if (m < Mc) {
        const int t = idx[m];
        float* orow = out + (size_t)t * HID + n0 + wc + fm;
#pragma unroll
        for (int j = 0; j < 4; ++j)
          orow[j * 16] = acc[i][j][r] + bias[n0 + wc + j * 16 + fm];
      }
    }
  }
}

// ---------------- launch ----------------
extern "C" void kernel_launch(void* const* d_in, const int* in_sizes, int n_in,
                              void* d_out, int out_size, void* d_ws, size_t ws_size,
                              hipStream_t stream) {
  const float* h   = (const float*)d_in[0];
  const float* Wg  = (const float*)d_in[3];
  const float* bg  = (const float*)d_in[4];
  const float* W1  = (const float*)d_in[5];
  const float* b1  = (const float*)d_in[6];
  const float* W2  = (const float*)d_in[7];
  const float* b2  = (const float*)d_in[8];
  const int*  labels = (const int*)d_in[9];
  float* out = (float*)d_out;

  char* ws = (char*)d_ws;
  int* cnt            = (int*)(ws + 0);
  int* idx            = (int*)(ws + 1024);
  __hip_bfloat16* W1t = (__hip_bfloat16*)(ws + (1u  << 17));   // [FF][HID]
  __hip_bfloat16* W2t = (__hip_bfloat16*)(ws + (16u << 20));   // [HID][FF]
  __hip_bfloat16* A   = (__hip_bfloat16*)(ws + (32u << 20));   // [TOK][HID]
  __hip_bfloat16* Act = (__hip_bfloat16*)(ws + (64ull << 20)); // [TOK][FF]

  hipMemsetAsync(cnt, 0, 4, stream);
  k_transpose<<<dim3(FF / 32, HID / 32), dim3(32, 8), 0, stream>>>(W1, W1t, HID, FF);
  k_transpose<<<dim3(HID / 32, FF / 32), dim3(32, 8), 0, stream>>>(W2, W2t, FF, HID);
  k_gate<<<TOK, 256, 0, stream>>>(h, Wg, bg, labels, out, A, idx, cnt);
  k_gemm1<<<dim3(TOK / 128, FF / 128), 256, 0, stream>>>(A, W1t, b1, Act, cnt);
  k_gemm2<<<dim3(TOK / 128, HID / 128), 256, 0, stream>>>(Act, W2t, b2, idx, out, cnt);
}